// Round 4
// baseline (196.508 us; speedup 1.0000x reference)
//
#include <hip/hip_runtime.h>
#include <hip/hip_fp16.h>
#include <stdint.h>

static constexpr int Bc = 16, Cc = 256, Hc = 56, Wc = 56, Gc = 4, CGc = 64;
static constexpr int HWc = Hc * Wc;
static constexpr float EPSc = 1e-5f;

// ---------------------------------------------------------------------------
// Workspace layout:
//   ws + 0      : 1024 B zero area (zrow = ws + 64 B; reads zrow[-5..61] stay
//                 inside [0,1024) -> no fault, used cols [0,56) are zero)
//   ws + 1024   : abits, 200704 u64  (under/overflow of +-40 B lands in ws)
//   ws + 1606656: wbits, 6912 u64
//   ws + 1661952: scales, 768 f32
// ---------------------------------------------------------------------------

// ---------------------------------------------------------------------------
// K1: blocks [0,192): weight pack (4 (i,o) pairs per block, one per wave).
//     block 192   : zero the zero-area.
//     blocks 193+ : activation pack, one (b,h) row per block, coalesced
//                   float4 loads + LDS byte transpose -> 64-bit group words.
// ---------------------------------------------------------------------------
static constexpr int SBS = 260;  // sign-byte LDS row stride (keeps dword align)

__global__ __launch_bounds__(256) void k_prep(
    const float* __restrict__ w, const float* __restrict__ x,
    const float* __restrict__ bias, uint64_t* __restrict__ wbits,
    float* __restrict__ scales, uint64_t* __restrict__ abits,
    uint32_t* __restrict__ zero_area) {
  const int t = threadIdx.x;
  if (blockIdx.x < 192) {
    // ---- weight part: io = blockIdx*4 + wave ----
    const int io = blockIdx.x * 4 + (t >> 6);
    const int i = io >> 8, o = io & 255;
    const int lane = t & 63;
    const float* wp = w + (size_t)io * 576 + lane * 9;
    float v[9];
    float ssum = 0.f, sabs = 0.f;
#pragma unroll
    for (int k = 0; k < 9; ++k) {
      v[k] = wp[k];
      ssum += v[k];
      sabs += fabsf(v[k]);
    }
#pragma unroll
    for (int off = 32; off > 0; off >>= 1) {
      ssum += __shfl_down(ssum, off);
      sabs += __shfl_down(sabs, off);
    }
    const float mean = __shfl(ssum, 0) * (1.f / 576.f);
    const float scale = __shfl(sabs, 0) * (1.f / 576.f);
#pragma unroll
    for (int k = 0; k < 9; ++k) {
      unsigned long long m = __ballot(v[k] > mean);
      if (lane == 0) wbits[(i * 9 + k) * Cc + o] = m;
    }
    if (lane == 0) scales[io] = scale;
  } else if (blockIdx.x == 192) {
    zero_area[t] = 0;  // 256 u32 = 1024 B
  } else {
    // ---- activation part: one (b,h) row, all 256 channels ----
    __shared__ uint8_t sb[Wc * SBS];  // sb[w*SBS + c] = sign bit (14560 B)
    const int bid = blockIdx.x - 193;
    const int b = bid / Hc, h = bid % Hc;
    const float* xb = x + ((size_t)b * Cc) * HWc + h * Wc;
#pragma unroll
    for (int k = 0; k < 14; ++k) {
      const int idx = k * 256 + t;       // [0, 3584)
      const int c = idx / 14, q = idx - c * 14;
      const float4 v = *(const float4*)(xb + (size_t)c * HWc + q * 4);
      const float bc = bias[c];
      sb[(q * 4 + 0) * SBS + c] = (v.x + bc > 0.f);
      sb[(q * 4 + 1) * SBS + c] = (v.y + bc > 0.f);
      sb[(q * 4 + 2) * SBS + c] = (v.z + bc > 0.f);
      sb[(q * 4 + 3) * SBS + c] = (v.w + bc > 0.f);
    }
    __syncthreads();
    if (t < Gc * Wc) {  // 224 threads: (g, w)
      const int g = t / Wc, ww = t - g * Wc;
      const uint32_t* p = (const uint32_t*)(sb + ww * SBS + g * 64);
      uint64_t word = 0;
#pragma unroll
      for (int dw = 0; dw < 16; ++dw) {
        const uint32_t d = p[dw];  // 4 sign bytes (0/1)
        const uint32_t nib = (d | (d >> 7) | (d >> 14) | (d >> 21)) & 0xF;
        word |= (uint64_t)nib << (4 * dw);
      }
      abits[(((size_t)b * Gc + g) * Hc + h) * Wc + ww] = word;
    }
  }
}

// ---------------------------------------------------------------------------
// Per-branch conv state. Activation rows are loaded through WAVE-UNIFORM
// pointers (g via readfirstlane) -> scalar (SMEM) loads; taps are
// v_xor(sgpr)+v_bcnt. Invalid rows -> global zero row + B-constant folding
// (verified in R3). Col-validity folds at compile time (w unrolled).
// ---------------------------------------------------------------------------
template <int D>
struct Branch {
  uint64_t wgt[9];
  const uint64_t *r0, *r1, *r2;
  int BL, BM, BR;
  float sc, cbm1, al;

  __device__ __forceinline__ void init(const uint64_t* __restrict__ wb,
                                       const uint64_t* rowbase,
                                       const uint64_t* zrow, int h,
                                       float sc_, float cbm1_, float al_) {
    sc = sc_; cbm1 = cbm1_; al = al_;
    int z[9];
#pragma unroll
    for (int k = 0; k < 9; ++k) {
      wgt[k] = wb[k * Cc];
      z[k] = 64 - 2 * (int)__builtin_popcountll(wgt[k]);
    }
    const bool v0 = (h - D >= 0), v2 = (h + D < Hc);
    r0 = v0 ? (rowbase + (size_t)(h - D) * Wc) : zrow;
    r1 = rowbase + (size_t)h * Wc;
    r2 = v2 ? (rowbase + (size_t)(h + D) * Wc) : zrow;
    const int Z0 = (v0 ? 0 : z[0]) + (v2 ? 0 : z[6]);
    const int Z1 = (v0 ? 0 : z[1]) + (v2 ? 0 : z[7]);
    const int Z2 = (v0 ? 0 : z[2]) + (v2 ? 0 : z[8]);
    BM = 576 - Z0 - Z1 - Z2;
    BL = 384 - Z1 - Z2;
    BR = 384 - Z0 - Z1;
  }

  // accumulate popcounts for outputs [c0, c0+14); c0 compile-time constant
  __device__ __forceinline__ void accum(int c0, int acc[14]) const {
#pragma unroll
    for (int kh = 0; kh < 3; ++kh) {
      const uint64_t* rp = (kh == 0) ? r0 : (kh == 1 ? r1 : r2);
      uint64_t sa[14 + 2 * D];  // row segment, wave-uniform -> SGPRs
#pragma unroll
      for (int j = 0; j < 14 + 2 * D; ++j) sa[j] = rp[c0 - D + j];
#pragma unroll
      for (int ww = 0; ww < 14; ++ww) {
#pragma unroll
        for (int kw = 0; kw < 3; ++kw) {
          const int col = c0 + ww + D * (kw - 1);
          if (col < 0 || col >= Wc) continue;  // folds at compile time
          acc[ww] += (int)__builtin_popcountll(wgt[kh * 3 + kw] ^ sa[ww + D * kw]);
        }
      }
    }
  }

  __device__ __forceinline__ void epi(int c0, const int acc[14],
                                      float outf[14]) const {
#pragma unroll
    for (int ww = 0; ww < 14; ++ww) {
      const int wg = c0 + ww;
      const int B = (wg < D) ? BL : ((wg >= Wc - D) ? BR : BM);
      const float y0 = fmaf(sc, (float)(B - 2 * acc[ww]), cbm1);
      outf[ww] += fmaxf(y0, 0.f) + al * fminf(y0, 0.f);
    }
  }
};

// ---------------------------------------------------------------------------
// K2: fused conv(3 branches)+bias+RPReLU+sum+LayerNorm. block = (b,h) row,
// thread = output channel. No activation LDS: conv reads via scalar loads.
// LDS: fp16 out_tile[256][58] (29696 B) + stats (2240 B) -> 4 blocks/CU cap.
// ---------------------------------------------------------------------------
static constexpr int TS2 = 58;

__global__ __launch_bounds__(256, 4) void k_conv_ln(
    const uint64_t* __restrict__ abits, const uint64_t* __restrict__ zrow,
    const uint64_t* __restrict__ wbits, const float* __restrict__ scales,
    const float* __restrict__ cb, const float* __restrict__ mv1,
    const float* __restrict__ al, const float* __restrict__ mv2,
    const float* __restrict__ gamma, const float* __restrict__ beta,
    float* __restrict__ out) {
  __shared__ __half out_tile[Cc * TS2];
  __shared__ float redu[4][Wc], redq[4][Wc];
  __shared__ float mstat[Wc], rstat[Wc];

  const int bid = blockIdx.x;  // b*56 + h
  const int b = bid / Hc, h = bid % Hc;
  const int t = threadIdx.x;   // output channel
  const int gu = __builtin_amdgcn_readfirstlane(t >> 6);  // uniform group

  const uint64_t* rowbase = abits + ((size_t)b * Gc + gu) * Hc * Wc;

  Branch<1> b0; Branch<3> b1; Branch<5> b2;
  b0.init(wbits + 0 * 9 * Cc + t, rowbase, zrow, h, scales[0 * Cc + t],
          cb[0 * Cc + t] - mv1[0 * Cc + t], al[0 * Cc + t]);
  b1.init(wbits + 1 * 9 * Cc + t, rowbase, zrow, h, scales[1 * Cc + t],
          cb[1 * Cc + t] - mv1[1 * Cc + t], al[1 * Cc + t]);
  b2.init(wbits + 2 * 9 * Cc + t, rowbase, zrow, h, scales[2 * Cc + t],
          cb[2 * Cc + t] - mv1[2 * Cc + t], al[2 * Cc + t]);
  const float m2sum = mv2[0 * Cc + t] + mv2[1 * Cc + t] + mv2[2 * Cc + t];

#pragma unroll
  for (int ch = 0; ch < 4; ++ch) {
    const int c0 = ch * 14;
    float outf[14];
#pragma unroll
    for (int ww = 0; ww < 14; ++ww) outf[ww] = m2sum;
    { int acc[14] = {}; b0.accum(c0, acc); b0.epi(c0, acc, outf); }
    { int acc[14] = {}; b1.accum(c0, acc); b1.epi(c0, acc, outf); }
    { int acc[14] = {}; b2.accum(c0, acc); b2.epi(c0, acc, outf); }
#pragma unroll
    for (int ww = 0; ww < 14; ww += 2) {
      __half2 hv;
      hv.x = __float2half(outf[ww]);
      hv.y = __float2half(outf[ww + 1]);
      *(__half2*)&out_tile[t * TS2 + c0 + ww] = hv;
    }
  }
  __syncthreads();

  // ---- LN stats ----
  if (t < 4 * Wc) {
    const int ww = t % Wc;
    const int cq = t / Wc;
    float s = 0.f, sq = 0.f;
#pragma unroll 4
    for (int c = cq * 64; c < cq * 64 + 64; ++c) {
      const float v = __half2float(out_tile[c * TS2 + ww]);
      s += v;
      sq = fmaf(v, v, sq);
    }
    redu[cq][ww] = s;
    redq[cq][ww] = sq;
  }
  __syncthreads();
  if (t < Wc) {
    const float s = redu[0][t] + redu[1][t] + redu[2][t] + redu[3][t];
    const float sq = redq[0][t] + redq[1][t] + redq[2][t] + redq[3][t];
    const float mean = s * (1.f / 256.f);
    const float var = sq * (1.f / 256.f) - mean * mean;
    mstat[t] = mean;
    rstat[t] = rsqrtf(var + EPSc);
  }
  __syncthreads();

  // ---- normalize + coalesced store ----
  float* base = out + ((size_t)b * Cc * Hc + h) * Wc;
  for (int idx = t; idx < Cc * Wc; idx += 256) {
    const int c = idx / Wc;
    const int ww = idx - c * Wc;
    const float v = __half2float(out_tile[c * TS2 + ww]);
    base[(size_t)c * HWc + ww] = (v - mstat[ww]) * rstat[ww] * gamma[c] + beta[c];
  }
}

// ---------------------------------------------------------------------------
extern "C" void kernel_launch(void* const* d_in, const int* in_sizes, int n_in,
                              void* d_out, int out_size, void* d_ws, size_t ws_size,
                              hipStream_t stream) {
  const float* x     = (const float*)d_in[0];
  const float* bias  = (const float*)d_in[1];
  const float* w     = (const float*)d_in[2];
  const float* cb    = (const float*)d_in[3];
  const float* mv1   = (const float*)d_in[4];
  const float* al    = (const float*)d_in[5];
  const float* mv2   = (const float*)d_in[6];
  const float* gamma = (const float*)d_in[7];
  const float* beta  = (const float*)d_in[8];
  float* out = (float*)d_out;

  uint8_t* ws = (uint8_t*)d_ws;
  uint32_t* zero_area = (uint32_t*)ws;                        // 1024 B
  const uint64_t* zrow = (const uint64_t*)(ws + 64);          // inside zeros
  uint64_t* abits = (uint64_t*)(ws + 1024);                   // 200704*8 B
  uint64_t* wbits = (uint64_t*)(ws + 1024 + (size_t)200704 * 8);
  float* scales   = (float*)(ws + 1024 + (size_t)200704 * 8 + 6912 * 8);

  hipLaunchKernelGGL(k_prep, dim3(192 + 1 + Bc * Hc), dim3(256), 0, stream,
                     w, x, bias, wbits, scales, abits, zero_area);
  hipLaunchKernelGGL(k_conv_ln, dim3(Bc * Hc), dim3(256), 0, stream,
                     abits, zrow, wbits, scales, cb, mv1, al, mv2, gamma, beta,
                     out);
}

// Round 5
// 186.657 us; speedup vs baseline: 1.0528x; 1.0528x over previous
//
#include <hip/hip_runtime.h>
#include <hip/hip_fp16.h>
#include <stdint.h>

static constexpr int Bc = 16, Cc = 256, Hc = 56, Wc = 56, Gc = 4, CGc = 64;
static constexpr int HWc = Hc * Wc;
static constexpr float EPSc = 1e-5f;
static constexpr int ROWP = 72;   // padded abits row: [8 zero | 56 data | 8 zero]
static constexpr int COL0 = 8;

// ---------------------------------------------------------------------------
// Workspace:
//   ws + 0       : 1024 B zero area (zrowp = ws + 8 u64; conv reads
//                  zrowp[-5..61) -> bytes [24, 552) -> inside, all zero)
//   ws + 1024    : abits_pad [16][4][56][72] u64 = 2,064,384 B
//   ws + 2065408 : wbits [3][9][256] u64 = 55,296 B
//   ws + 2120704 : scales [768] f32
// ---------------------------------------------------------------------------

static constexpr int SBS = 260;  // sign-byte LDS row stride (4B-aligned)

__global__ __launch_bounds__(256) void k_prep(
    const float* __restrict__ w, const float* __restrict__ x,
    const float* __restrict__ bias, uint64_t* __restrict__ wbits,
    float* __restrict__ scales, uint64_t* __restrict__ abits,
    uint32_t* __restrict__ zero_area) {
  const int t = threadIdx.x;
  if (blockIdx.x < 192) {
    // ---- weight pack: io = blockIdx*4 + wave ----
    const int io = blockIdx.x * 4 + (t >> 6);
    const int i = io >> 8, o = io & 255;
    const int lane = t & 63;
    const float* wp = w + (size_t)io * 576 + lane * 9;
    float v[9];
    float ssum = 0.f, sabs = 0.f;
#pragma unroll
    for (int k = 0; k < 9; ++k) {
      v[k] = wp[k];
      ssum += v[k];
      sabs += fabsf(v[k]);
    }
#pragma unroll
    for (int off = 32; off > 0; off >>= 1) {
      ssum += __shfl_down(ssum, off);
      sabs += __shfl_down(sabs, off);
    }
    const float mean = __shfl(ssum, 0) * (1.f / 576.f);
    const float scale = __shfl(sabs, 0) * (1.f / 576.f);
#pragma unroll
    for (int k = 0; k < 9; ++k) {
      unsigned long long m = __ballot(v[k] > mean);
      if (lane == 0) wbits[(i * 9 + k) * Cc + o] = m;
    }
    if (lane == 0) scales[io] = scale;
  } else if (blockIdx.x == 192) {
    zero_area[t] = 0;  // 1024 B
  } else {
    // ---- activation pack: one (b,h) row, coalesced + LDS byte transpose ----
    __shared__ uint8_t sb[Wc * SBS];
    const int bid = blockIdx.x - 193;
    const int b = bid / Hc, h = bid % Hc;
    const float* xb = x + ((size_t)b * Cc) * HWc + h * Wc;
#pragma unroll
    for (int k = 0; k < 14; ++k) {
      const int idx = k * 256 + t;  // [0, 3584)
      const int c = idx / 14, q = idx - c * 14;
      const float4 v = *(const float4*)(xb + (size_t)c * HWc + q * 4);
      const float bc = bias[c];
      sb[(q * 4 + 0) * SBS + c] = (v.x + bc > 0.f);
      sb[(q * 4 + 1) * SBS + c] = (v.y + bc > 0.f);
      sb[(q * 4 + 2) * SBS + c] = (v.z + bc > 0.f);
      sb[(q * 4 + 3) * SBS + c] = (v.w + bc > 0.f);
    }
    __syncthreads();
    // write padded rows: 4 groups x 72 words (zeros in the pads)
    for (int idx = t; idx < Gc * ROWP; idx += 256) {
      const int g = idx / ROWP, k = idx - g * ROWP;
      uint64_t word = 0;
      if (k >= COL0 && k < COL0 + Wc) {
        const int ww = k - COL0;
        const uint32_t* p = (const uint32_t*)(sb + ww * SBS + g * 64);
        uint64_t acc = 0;
#pragma unroll
        for (int dw = 0; dw < 16; ++dw) {
          const uint32_t d = p[dw];
          const uint32_t nib = (d | (d >> 7) | (d >> 14) | (d >> 21)) & 0xF;
          acc |= (uint64_t)nib << (4 * dw);
        }
        word = acc;
      }
      abits[(((size_t)b * Gc + g) * Hc + h) * ROWP + idx - g * ROWP +
            (size_t)g * 0] = 0;  // placeholder overwritten below
      abits[(((size_t)b * Gc + g) * Hc + h) * ROWP + k] = word;
    }
  }
}

// ---------------------------------------------------------------------------
// Per-branch conv state. Row pointers are wave-uniform (group via
// readfirstlane); segments of 8+2D u64 are loaded per (kh) -> small enough
// to live in SGPRs (<=36). Rows out of bounds -> zero area; cols out of
// bounds -> zero padding in abits rows. Exact integer correction:
//   B(w) = 576 - Zrow - (w<D)?ZL:0 - (w>=56-D)?ZR:0;  dot = B - 2*sum popc
// ---------------------------------------------------------------------------
template <int D>
struct Branch {
  uint64_t wgt[9];
  const uint64_t *r0, *r1, *r2;  // point at col 0 of each kh row
  int BM, ZL, ZR;
  float sc, cbm1, al;

  __device__ __forceinline__ void init(const uint64_t* __restrict__ wb,
                                       const uint64_t* rowbase,  // col0,row0
                                       const uint64_t* zrowp, int h,
                                       float sc_, float cbm1_, float al_) {
    sc = sc_; cbm1 = cbm1_; al = al_;
    int z[9];
#pragma unroll
    for (int k = 0; k < 9; ++k) {
      wgt[k] = wb[k * Cc];
      z[k] = 64 - 2 * (int)__builtin_popcountll(wgt[k]);
    }
    const bool v0 = (h - D >= 0), v2 = (h + D < Hc);
    r0 = v0 ? (rowbase + (size_t)(h - D) * ROWP) : zrowp;
    r1 = rowbase + (size_t)h * ROWP;
    r2 = v2 ? (rowbase + (size_t)(h + D) * ROWP) : zrowp;
    const int Zrow = (v0 ? 0 : (z[0] + z[1] + z[2])) +
                     (v2 ? 0 : (z[6] + z[7] + z[8]));
    BM = 576 - Zrow;
    ZL = (v0 ? z[0] : 0) + z[3] + (v2 ? z[6] : 0);
    ZR = (v0 ? z[2] : 0) + z[5] + (v2 ? z[8] : 0);
  }

  // accumulate popcounts for outputs [w0, w0+8)
  __device__ __forceinline__ void accum8(int w0, int acc[8]) const {
#pragma unroll
    for (int kh = 0; kh < 3; ++kh) {
      const uint64_t* rp = (kh == 0) ? r0 : (kh == 1 ? r1 : r2);
      uint64_t seg[8 + 2 * D];  // wave-uniform -> SGPRs
#pragma unroll
      for (int j = 0; j < 8 + 2 * D; ++j) seg[j] = rp[w0 - D + j];
#pragma unroll
      for (int ww = 0; ww < 8; ++ww) {
#pragma unroll
        for (int kw = 0; kw < 3; ++kw)
          acc[ww] +=
              (int)__builtin_popcountll(wgt[kh * 3 + kw] ^ seg[ww + D * kw]);
      }
    }
  }

  __device__ __forceinline__ void epi8(int w0, const int acc[8],
                                       float outf[8]) const {
#pragma unroll
    for (int ww = 0; ww < 8; ++ww) {
      const int w = w0 + ww;
      const int B = BM - ((w < D) ? ZL : 0) - ((w >= Wc - D) ? ZR : 0);
      const float y0 = fmaf(sc, (float)(B - 2 * acc[ww]), cbm1);
      outf[ww] += fmaxf(y0, 0.f) + al * fminf(y0, 0.f);
    }
  }
};

// ---------------------------------------------------------------------------
// K2: fused conv(3 branches)+bias+RPReLU+sum+LayerNorm. block = (b,h) row,
// thread = output channel. Activations via scalar-load segments; no LDS for
// activations. LDS: fp16 out_tile + stats ~31.9 KB -> 4 blocks/CU.
// ---------------------------------------------------------------------------
static constexpr int TS2 = 58;

__global__ __launch_bounds__(256, 4) void k_conv_ln(
    const uint64_t* __restrict__ abits, const uint64_t* __restrict__ zrowp,
    const uint64_t* __restrict__ wbits, const float* __restrict__ scales,
    const float* __restrict__ cb, const float* __restrict__ mv1,
    const float* __restrict__ al, const float* __restrict__ mv2,
    const float* __restrict__ gamma, const float* __restrict__ beta,
    float* __restrict__ out) {
  __shared__ __half out_tile[Cc * TS2];
  __shared__ float redu[4][Wc], redq[4][Wc];
  __shared__ float mstat[Wc], rstat[Wc];

  const int bid = blockIdx.x;  // b*56 + h
  const int b = bid / Hc, h = bid % Hc;
  const int t = threadIdx.x;   // output channel
  const int gu = __builtin_amdgcn_readfirstlane(t >> 6);

  const uint64_t* rowbase = abits + ((size_t)b * Gc + gu) * Hc * ROWP + COL0;

  Branch<1> b0; Branch<3> b1; Branch<5> b2;
  b0.init(wbits + 0 * 9 * Cc + t, rowbase, zrowp, h, scales[0 * Cc + t],
          cb[0 * Cc + t] - mv1[0 * Cc + t], al[0 * Cc + t]);
  b1.init(wbits + 1 * 9 * Cc + t, rowbase, zrowp, h, scales[1 * Cc + t],
          cb[1 * Cc + t] - mv1[1 * Cc + t], al[1 * Cc + t]);
  b2.init(wbits + 2 * 9 * Cc + t, rowbase, zrowp, h, scales[2 * Cc + t],
          cb[2 * Cc + t] - mv1[2 * Cc + t], al[2 * Cc + t]);
  const float m2sum = mv2[0 * Cc + t] + mv2[1 * Cc + t] + mv2[2 * Cc + t];

  for (int ch = 0; ch < 7; ++ch) {  // runtime loop: keeps live ranges small
    const int w0 = ch * 8;
    float outf[8];
#pragma unroll
    for (int ww = 0; ww < 8; ++ww) outf[ww] = m2sum;
    { int acc[8] = {}; b0.accum8(w0, acc); b0.epi8(w0, acc, outf); }
    { int acc[8] = {}; b1.accum8(w0, acc); b1.epi8(w0, acc, outf); }
    { int acc[8] = {}; b2.accum8(w0, acc); b2.epi8(w0, acc, outf); }
#pragma unroll
    for (int ww = 0; ww < 8; ww += 2) {
      __half2 hv;
      hv.x = __float2half(outf[ww]);
      hv.y = __float2half(outf[ww + 1]);
      *(__half2*)&out_tile[t * TS2 + w0 + ww] = hv;
    }
  }
  __syncthreads();

  // ---- LN stats ----
  if (t < 4 * Wc) {
    const int ww = t % Wc;
    const int cq = t / Wc;
    float s = 0.f, sq = 0.f;
#pragma unroll 4
    for (int c = cq * 64; c < cq * 64 + 64; ++c) {
      const float v = __half2float(out_tile[c * TS2 + ww]);
      s += v;
      sq = fmaf(v, v, sq);
    }
    redu[cq][ww] = s;
    redq[cq][ww] = sq;
  }
  __syncthreads();
  if (t < Wc) {
    const float s = redu[0][t] + redu[1][t] + redu[2][t] + redu[3][t];
    const float sq = redq[0][t] + redq[1][t] + redq[2][t] + redq[3][t];
    const float mean = s * (1.f / 256.f);
    const float var = sq * (1.f / 256.f) - mean * mean;
    mstat[t] = mean;
    rstat[t] = rsqrtf(var + EPSc);
  }
  __syncthreads();

  // ---- normalize + coalesced store ----
  float* base = out + ((size_t)b * Cc * Hc + h) * Wc;
  for (int idx = t; idx < Cc * Wc; idx += 256) {
    const int c = idx / Wc;
    const int ww = idx - c * Wc;
    const float v = __half2float(out_tile[c * TS2 + ww]);
    base[(size_t)c * HWc + ww] = (v - mstat[ww]) * rstat[ww] * gamma[c] + beta[c];
  }
}

// ---------------------------------------------------------------------------
extern "C" void kernel_launch(void* const* d_in, const int* in_sizes, int n_in,
                              void* d_out, int out_size, void* d_ws, size_t ws_size,
                              hipStream_t stream) {
  const float* x     = (const float*)d_in[0];
  const float* bias  = (const float*)d_in[1];
  const float* w     = (const float*)d_in[2];
  const float* cb    = (const float*)d_in[3];
  const float* mv1   = (const float*)d_in[4];
  const float* al    = (const float*)d_in[5];
  const float* mv2   = (const float*)d_in[6];
  const float* gamma = (const float*)d_in[7];
  const float* beta  = (const float*)d_in[8];
  float* out = (float*)d_out;

  uint8_t* ws = (uint8_t*)d_ws;
  uint32_t* zero_area = (uint32_t*)ws;
  const uint64_t* zrowp = (const uint64_t*)ws + COL0;
  uint64_t* abits = (uint64_t*)(ws + 1024);
  const size_t abits_bytes = (size_t)Bc * Gc * Hc * ROWP * 8;  // 2,064,384
  uint64_t* wbits = (uint64_t*)(ws + 1024 + abits_bytes);
  float* scales = (float*)(ws + 1024 + abits_bytes + 6912 * 8);

  hipLaunchKernelGGL(k_prep, dim3(192 + 1 + Bc * Hc), dim3(256), 0, stream,
                     w, x, bias, wbits, scales, abits, zero_area);
  hipLaunchKernelGGL(k_conv_ln, dim3(Bc * Hc), dim3(256), 0, stream,
                     abits, zrowp, wbits, scales, cb, mv1, al, mv2, gamma, beta,
                     out);
}